// Round 4
// baseline (463.866 us; speedup 1.0000x reference)
//
#include <hip/hip_runtime.h>
#include <cfloat>

constexpr int kN = 131072;
constexpr int kC = 128;
constexpr int kRowsPerBlock = 64;   // 4 waves x 16 rows each

__device__ __forceinline__ unsigned fmap(float f) {
    unsigned b = __float_as_uint(f);
    return (b & 0x80000000u) ? ~b : (b | 0x80000000u);
}

// DPP lane-permute move within 16-lane rows (pure VALU, no DS pipe)
template<int CTRL>
__device__ __forceinline__ float dppmov(float x) {
    return __int_as_float(__builtin_amdgcn_update_dpp(
        __float_as_int(x), __float_as_int(x), CTRL, 0xF, 0xF, false));
}

// merge two disjoint (top1, top2) pairs
__device__ __forceinline__ void top2_merge(float& m1, float& m2, float o1, float o2) {
    const float lo = fminf(m1, o1);
    m1 = fmaxf(m1, o1);
    m2 = fmaxf(fmaxf(m2, o2), lo);
}

__global__ __launch_bounds__(256, 8) void margins_kernel(
    const float* __restrict__ p0, const float* __restrict__ p1,
    const float* __restrict__ p2, const float* __restrict__ p3,
    const float* __restrict__ p4, const float* __restrict__ p5,
    const float* __restrict__ p6, const float* __restrict__ p7,
    const int* __restrict__ targets, float* __restrict__ out,
    unsigned* __restrict__ gmax_ws)
{
    __shared__ float marg_lds[kRowsPerBlock][9];   // [local row][pred], pitch 9
    __shared__ unsigned blockmax;

    const int t = threadIdx.x;
    if (t == 0) blockmax = 0u;
    __syncthreads();

    const float* preds[8] = {p0, p1, p2, p3, p4, p5, p6, p7};

    const int l   = t & 63;          // lane in wave
    const int w   = t >> 6;          // wave id, 0..3
    const int myl = l & 15;          // lane within 16-lane row group
    const int rg  = l >> 4;          // row group within wave, 0..3
    const int R0  = blockIdx.x * kRowsPerBlock + w * 16;   // wave's first row

    // lane's byte offset of (row R0+rg, col myl*4), first half of the row
    const size_t base_off = ((size_t)(R0 + rg) * kC + myl * 4) * sizeof(float);

    int tg[4];
#pragma unroll
    for (int it = 0; it < 4; ++it) tg[it] = targets[R0 + it * 4 + rg];

    float gm = -FLT_MAX;

    // 4-deep ring: group g = (pred j = g>>2, iter it = g&3); 8 loads in flight
    float4 A[4], B[4];
#pragma unroll
    for (int g = 0; g < 4; ++g) {
        const char* p = (const char*)preds[g >> 2] + base_off
                      + (size_t)(g & 3) * 4 * kC * sizeof(float);
        A[g] = *(const float4*)p;
        B[g] = *(const float4*)(p + 256);
    }

#pragma unroll
    for (int g = 0; g < 32; ++g) {
        const int j  = g >> 2;
        const int it = g & 3;

        const float4 va = A[g & 3];
        const float4 vb = B[g & 3];

        if (g + 4 < 32) {   // refill this slot from 4 groups ahead
            const int gn = g + 4;
            const char* p = (const char*)preds[gn >> 2] + base_off
                          + (size_t)(gn & 3) * 4 * kC * sizeof(float);
            A[g & 3] = *(const float4*)p;
            B[g & 3] = *(const float4*)(p + 256);
        }
        __builtin_amdgcn_sched_barrier(0);

        // ---- in-lane top2 of 8 ----
        float a1 = fmaxf(va.x, va.y), a2 = fminf(va.x, va.y);
        float b1 = fmaxf(va.z, va.w), b2 = fminf(va.z, va.w);
        const float mA1 = fmaxf(a1, b1);
        const float mA2 = fmaxf(fminf(a1, b1), fmaxf(a2, b2));
        a1 = fmaxf(vb.x, vb.y); a2 = fminf(vb.x, vb.y);
        b1 = fmaxf(vb.z, vb.w); b2 = fminf(vb.z, vb.w);
        const float mB1 = fmaxf(a1, b1);
        const float mB2 = fmaxf(fminf(a1, b1), fmaxf(a2, b2));
        float m1 = mA1, m2 = mA2;
        top2_merge(m1, m2, mB1, mB2);

        // ---- 16-lane butterfly, all DPP (VALU pipe); every lane ends with row top2 ----
        { const float o1 = dppmov<0xB1>(m1),  o2 = dppmov<0xB1>(m2);  top2_merge(m1, m2, o1, o2); }
        { const float o1 = dppmov<0x4E>(m1),  o2 = dppmov<0x4E>(m2);  top2_merge(m1, m2, o1, o2); }
        { const float o1 = dppmov<0x124>(m1), o2 = dppmov<0x124>(m2); top2_merge(m1, m2, o1, o2); }
        { const float o1 = dppmov<0x128>(m1), o2 = dppmov<0x128>(m2); top2_merge(m1, m2, o1, o2); }

        // ---- holder lane computes margin directly (no broadcast needed) ----
        const int tt = tg[it];
        const float4 hv = (tt & 64) ? vb : va;
        const int el = tt & 3;
        const float tv = (el == 0) ? hv.x : (el == 1) ? hv.y : (el == 2) ? hv.z : hv.w;
        const float margin = (tv == m1) ? (m1 - m2) : 0.0f;
        if (myl == ((tt >> 2) & 15)) marg_lds[w * 16 + it * 4 + rg][j] = margin;
        if (j < 7) gm = fmaxf(gm, m1);
    }

    // ---- per-wave softmax + contiguous store (512 B per wave) ----
    {
        const int rr = l >> 2;           // row within wave, 0..15
        const int q  = l & 3;            // quarter: stores outputs q*2, q*2+1
        float m[8];
#pragma unroll
        for (int jj = 0; jj < 8; ++jj) m[jj] = marg_lds[w * 16 + rr][jj];
        float mm = m[0];
#pragma unroll
        for (int jj = 1; jj < 8; ++jj) mm = fmaxf(mm, m[jj]);
        float e[8], s = 0.0f;
#pragma unroll
        for (int jj = 0; jj < 8; ++jj) { e[jj] = __expf((m[jj] - mm) * 0.5f); s += e[jj]; }
        const float inv = 1.0f / s;
        const float o0 = ((q == 0) ? e[0] : (q == 1) ? e[2] : (q == 2) ? e[4] : e[6]) * inv;
        const float o1 = ((q == 0) ? e[1] : (q == 1) ? e[3] : (q == 2) ? e[5] : e[7]) * inv;
        const size_t ob = 1 + ((size_t)(blockIdx.x * kRowsPerBlock + w * 16 + rr)) * 8 + q * 2;
        out[ob]     = o0;
        out[ob + 1] = o1;
    }

    // ---- block / global max over preds 0..6 ----
    gm = fmaxf(gm, __shfl_xor(gm, 16));
    gm = fmaxf(gm, __shfl_xor(gm, 32));
    if (l == 0) atomicMax(&blockmax, fmap(gm));
    __syncthreads();
    if (t == 0) atomicMax(gmax_ws, blockmax);
}

__global__ void finalize_kernel(const unsigned* __restrict__ gmax_ws,
                                float* __restrict__ out)
{
    unsigned u = *gmax_ws;
    unsigned b = (u & 0x80000000u) ? (u & 0x7FFFFFFFu) : ~u;
    out[0] = __uint_as_float(b);
}

extern "C" void kernel_launch(void* const* d_in, const int* in_sizes, int n_in,
                              void* d_out, int out_size, void* d_ws, size_t ws_size,
                              hipStream_t stream) {
    const float* p0 = (const float*)d_in[0];
    const float* p1 = (const float*)d_in[1];
    const float* p2 = (const float*)d_in[2];
    const float* p3 = (const float*)d_in[3];
    const float* p4 = (const float*)d_in[4];
    const float* p5 = (const float*)d_in[5];
    const float* p6 = (const float*)d_in[6];
    const float* p7 = (const float*)d_in[7];
    const int* targets = (const int*)d_in[8];
    float* out = (float*)d_out;
    unsigned* ws = (unsigned*)d_ws;

    hipMemsetAsync(ws, 0, sizeof(unsigned), stream);

    dim3 grid(kN / kRowsPerBlock), block(256);
    margins_kernel<<<grid, block, 0, stream>>>(p0, p1, p2, p3, p4, p5, p6, p7,
                                               targets, out, ws);
    finalize_kernel<<<1, 1, 0, stream>>>(ws, out);
}